// Round 5
// baseline (101.567 us; speedup 1.0000x reference)
//
#include <hip/hip_runtime.h>

#define IW 512
#define IH 512
#define NPLANES 48            // 16 batch * 3 channels
#define BLOCK 256             // 4 waves per block; each wave does 4 rows

typedef float v4f __attribute__((ext_vector_type(4)));

__device__ __forceinline__ void sort3(float& a, float& b, float& c) {
    float t;
    t = fminf(a, b); b = fmaxf(a, b); a = t;
    t = fminf(b, c); c = fmaxf(b, c); b = t;
    t = fminf(a, b); b = fmaxf(a, b); a = t;
}
__device__ __forceinline__ float med3f(float a, float b, float c) {
    return __builtin_amdgcn_fmed3f(a, b, c);
}
__device__ __forceinline__ float max3f(float a, float b, float c) {
    return fmaxf(fmaxf(a, b), c);
}
__device__ __forceinline__ float min3f(float a, float b, float c) {
    return fminf(fminf(a, b), c);
}

// One wave = 4 consecutive output rows of one plane; each lane owns 8 columns.
// 6 input rows loaded per wave (vs 12 for row-per-wave): halves VMEM insts
// and L2 re-reads.
__global__ __launch_bounds__(BLOCK) void median3x3_kernel(
    const float* __restrict__ x, float* __restrict__ out) {
    int tid  = blockIdx.x * BLOCK + threadIdx.x;
    int lane = threadIdx.x & 63;
    int w    = tid >> 6;            // global wave id
    int g    = w & 127;             // row-group within plane (512/4 = 128)
    int p    = w >> 7;              // plane
    int y0   = g << 2;              // first output row of this wave
    int x0   = lane << 3;           // first of 8 columns owned by this lane

    const float* plane = x + (size_t)p * IH * IW;

    // 6 source rows y0-1 .. y0+4 with reflect padding (pad = 1)
    int ridx[6];
    ridx[0] = (y0 == 0) ? 1 : y0 - 1;
    ridx[1] = y0;
    ridx[2] = y0 + 1;
    ridx[3] = y0 + 2;
    ridx[4] = y0 + 3;
    ridx[5] = (y0 + 4 == IH) ? IH - 2 : y0 + 4;

    // load all 6 rows x 8 cols up front: 12 coalesced float4 loads, deep ILP
    float r[6][8];
#pragma unroll
    for (int i = 0; i < 6; i++) {
        const float* rp = plane + (size_t)ridx[i] * IW + x0;
        v4f a = *(const v4f*)(rp);
        v4f b = *(const v4f*)(rp + 4);
        r[i][0] = a.x; r[i][1] = a.y; r[i][2] = a.z; r[i][3] = a.w;
        r[i][4] = b.x; r[i][5] = b.y; r[i][6] = b.z; r[i][7] = b.w;
    }

    float* dst0 = out + (size_t)p * IH * IW + (size_t)y0 * IW + x0;

#pragma unroll
    for (int t = 0; t < 4; t++) {
        // vertical sort of each owned column for triple (t, t+1, t+2)
        float lo[10], mi[10], hi[10];   // [0]=left halo, [1..8]=own, [9]=right halo
#pragma unroll
        for (int k = 0; k < 8; k++) {
            float a = r[t][k], b = r[t + 1][k], c = r[t + 2][k];
            sort3(a, b, c);
            lo[k + 1] = a; mi[k + 1] = b; hi[k + 1] = c;
        }

        // halo exchange of SORTED triples via wave shuffles
        float Ll = __shfl_up(lo[8], 1, 64);
        float Lm = __shfl_up(mi[8], 1, 64);
        float Lh = __shfl_up(hi[8], 1, 64);
        float Rl = __shfl_down(lo[1], 1, 64);
        float Rm = __shfl_down(mi[1], 1, 64);
        float Rh = __shfl_down(hi[1], 1, 64);
        if (lane == 0)  { Ll = lo[2]; Lm = mi[2]; Lh = hi[2]; }  // reflect col -1 -> 1
        if (lane == 63) { Rl = lo[7]; Rm = mi[7]; Rh = hi[7]; }  // reflect col 512 -> 510
        lo[0] = Ll; mi[0] = Lm; hi[0] = Lh;
        lo[9] = Rl; mi[9] = Rm; hi[9] = Rh;

        // horizontal merge: median9 = med3(max3(lo), med3(mi), min3(hi))
        float o[8];
#pragma unroll
        for (int j = 0; j < 8; j++) {
            float M = max3f(lo[j], lo[j + 1], lo[j + 2]);
            float m = med3f(mi[j], mi[j + 1], mi[j + 2]);
            float n = min3f(hi[j], hi[j + 1], hi[j + 2]);
            o[j] = med3f(M, m, n);
        }

        float* dst = dst0 + (size_t)t * IW;
        v4f r0 = {o[0], o[1], o[2], o[3]};
        v4f r1 = {o[4], o[5], o[6], o[7]};
        __builtin_nontemporal_store(r0, (v4f*)dst);
        __builtin_nontemporal_store(r1, (v4f*)(dst + 4));
    }
}

extern "C" void kernel_launch(void* const* d_in, const int* in_sizes, int n_in,
                              void* d_out, int out_size, void* d_ws, size_t ws_size,
                              hipStream_t stream) {
    const float* x = (const float*)d_in[0];
    float* out = (float*)d_out;
    // waves = 48 planes * 128 row-groups = 6144 ; threads = 6144*64 = 393216
    int total = NPLANES * 128 * 64;
    int blocks = total / BLOCK;   // 1536
    median3x3_kernel<<<blocks, BLOCK, 0, stream>>>(x, out);
}